// Round 6
// baseline (343.510 us; speedup 1.0000x reference)
//
#include <hip/hip_runtime.h>
#include <hip/hip_bf16.h>

// ---------------- constants (problem shape) ----------------
// B=2, S=2048, H=2048, NH=16, LD=512, HD=128
#define PB   2
#define PS   2048
#define PH   2048
#define PNH  16
#define PLD  512
#define PHD  128
#define PM   (PB * PS)          // 4096 rows in all GEMMs
#define PNCAT 3072              // merged down-proj width: 2048 q + 512 klat + 512 vlat
#define ATT_SCALE 0.08838834764831845f  // 1/sqrt(128)
#define ATT_MOFF 4.0f

typedef __attribute__((ext_vector_type(8))) short bf16x8;
typedef __attribute__((ext_vector_type(4))) float f32x4;

__device__ __forceinline__ unsigned short f2bf(float f) {
    unsigned int u = __float_as_uint(f);
    u += 0x7FFFu + ((u >> 16) & 1u);   // RNE
    return (unsigned short)(u >> 16);
}

// async global->LDS, 16 B per lane; LDS dest = wave-uniform base + lane*16
__device__ __forceinline__ void gl_lds16(const unsigned short* g, unsigned short* l) {
    __builtin_amdgcn_global_load_lds(
        (const __attribute__((address_space(1))) unsigned int*)g,
        (__attribute__((address_space(3))) unsigned int*)l, 16, 0, 0);
}

#define VMCNT(n)     asm volatile("s_waitcnt vmcnt(" #n ")" ::: "memory")

// ---------------- cast fp32 -> bf16 (elementwise, 4/thread) ----------------
__global__ __launch_bounds__(256) void cast_f32_bf16_kernel(
    const float* __restrict__ in, unsigned short* __restrict__ out, int n)
{
    int i = (blockIdx.x * 256 + threadIdx.x) * 4;
    if (i >= n) return;
    float4 f = *(const float4*)(in + i);
    unsigned int a = (unsigned int)f2bf(f.x) | ((unsigned int)f2bf(f.y) << 16);
    unsigned int b = (unsigned int)f2bf(f.z) | ((unsigned int)f2bf(f.w) << 16);
    *(uint2*)(out + i) = make_uint2(a, b);
}

// ---------------- transpose + cast: in fp32 [R][C] -> out bf16 [C][R] ----------------
__global__ __launch_bounds__(256) void transpose_cast_kernel(
    const float* __restrict__ in, unsigned short* __restrict__ out, int R, int C)
{
    __shared__ float tile[32][33];
    int tx = threadIdx.x, ty = threadIdx.y;
    int r0 = blockIdx.y * 32, c0 = blockIdx.x * 32;
#pragma unroll
    for (int i = 0; i < 32; i += 8)
        tile[ty + i][tx] = in[(size_t)(r0 + ty + i) * C + (c0 + tx)];
    __syncthreads();
#pragma unroll
    for (int i = 0; i < 32; i += 8)
        out[(size_t)(c0 + ty + i) * R + (r0 + tx)] = f2bf(tile[tx][ty + i]);
}

// ---------------- m97-structure bf16 MFMA GEMM: 128x128, multi-WG TLP ----------------
// R1-R5 lesson: 1-WG/CU schedules (96-128 KiB LDS) pin MfmaUtil at 26% -- all
// 8 waves share every barrier, nothing fills the drain windows.  m97 structure
// (912 TF proven, learn_hip m103): small LDS + 3 co-resident WGs/CU; barrier
// drains of one WG overlap compute of the others (m114 implicit overlap).
// 128x128 tile, BK=64, 256 threads = 4 waves (2x2, per-wave 64x64 out).
// Single-buffered 32 KiB LDS -> 3 WGs/CU (VGPR-capped via launch_bounds).
// Per K-step: 8x global_load_lds(w16) -> vmcnt(0)+syncthreads -> 16 ds_read_b128
// + 32 MFMA, compiler-scheduled (no fences) -> syncthreads.
// LDS XOR-swizzle via pre-swizzled global source (linear gl_lds dest) +
// swizzled ds_read: 0 bank conflicts (verified R1-R5).
// EPI: 0 = bf16 row-major, 1 = fp32 row-major, 2 = K-swizzled, 3 = V-swizzled.
template<int EPI, bool HAS_BIAS>
__global__ __launch_bounds__(256, 3) void gemm97_kernel(
    const unsigned short* __restrict__ A, int lda,
    const unsigned short* __restrict__ BT,
    const float* __restrict__ bias, int nbias,
    void* __restrict__ Cout, int ldc, int K)
{
    __shared__ __align__(16) unsigned short As[128 * 64];   // 16 KiB
    __shared__ __align__(16) unsigned short Bs[128 * 64];   // 16 KiB

    const int tid  = threadIdx.x;
    const int wave = tid >> 6, lane = tid & 63;
    const int wm = wave >> 1, wn = wave & 1;
    const int quad = lane >> 4, l15 = lane & 15;
    const int sw = l15 & 7;        // read-side XOR (== row&7 of every frag row)

    // bijective XCD-aware swizzle of the linear workgroup id
    const int gx  = gridDim.x;
    const int nwg = gx * gridDim.y;
    int wg = blockIdx.y * gx + blockIdx.x;
    if (!(nwg & 7)) wg = (wg & 7) * (nwg >> 3) + (wg >> 3);
    const int bm = (wg / gx) * 128, bn = (wg % gx) * 128;

    const int nt = K >> 6;

    // staging: thread t covers (row = t>>3 in 0..31, 16B-slot p = t&7) of a
    // 32x64 sweep; 4 sweeps cover 128 rows.  LDS dest linear => fetch the
    // pre-swizzled global column (phys slot p holds logical slot p^(row&7)).
    const int srow = tid >> 3;
    const int scol = ((tid & 7) ^ (srow & 7)) << 3;  // elements; (srow+32k)&7 invariant
    const unsigned short* Ag = A  + (size_t)(bm + srow) * lda + scol;
    const unsigned short* Bg = BT + (size_t)(bn + srow) * K   + scol;
    unsigned short* const ldsA = &As[wave * 512];
    unsigned short* const ldsB = &Bs[wave * 512];

    // fragment reads: logical (row, slot s=ks*4+quad) -> physical slot s^(row&7)
    auto ldA = [&](int m, int ks) -> bf16x8 {
        int ra = wm * 64 + m * 16 + l15;
        return *(const bf16x8*)&As[ra * 64 + (((ks * 4 + quad) ^ sw) << 3)];
    };
    auto ldB = [&](int j, int ks) -> bf16x8 {
        int rb = wn * 64 + j * 16 + l15;
        return *(const bf16x8*)&Bs[rb * 64 + (((ks * 4 + quad) ^ sw) << 3)];
    };

    f32x4 acc[4][4] = {};

    for (int kt = 0; kt < nt; ++kt) {
        const int k0 = kt * 64;
        // ---- stage tile kt: 4 sweeps x (A,B), 8 x global_load_lds ----
#pragma unroll
        for (int s = 0; s < 4; ++s) {
            gl_lds16(Ag + (size_t)(s * 32) * lda + k0, ldsA + s * 2048);
            gl_lds16(Bg + (size_t)(s * 32) * K   + k0, ldsB + s * 2048);
        }
        VMCNT(0);
        __syncthreads();   // tile visible to all waves

        // ---- compute: 16 ds_read_b128 + 32 MFMA, compiler-scheduled ----
        bf16x8 bfr[4][2];
#pragma unroll
        for (int j = 0; j < 4; ++j)
#pragma unroll
            for (int ks = 0; ks < 2; ++ks) bfr[j][ks] = ldB(j, ks);
#pragma unroll
        for (int m = 0; m < 4; ++m) {
            bf16x8 a0 = ldA(m, 0), a1 = ldA(m, 1);
#pragma unroll
            for (int j = 0; j < 4; ++j) {
                acc[m][j] = __builtin_amdgcn_mfma_f32_16x16x32_bf16(a0, bfr[j][0], acc[m][j], 0, 0, 0);
                acc[m][j] = __builtin_amdgcn_mfma_f32_16x16x32_bf16(a1, bfr[j][1], acc[m][j], 0, 0, 0);
            }
        }
        __syncthreads();   // all reads done before next tile's staging lands
    }

    // ---------- epilogue ----------
#pragma unroll
    for (int m = 0; m < 4; ++m)
#pragma unroll
        for (int j = 0; j < 4; ++j)
#pragma unroll
            for (int r = 0; r < 4; ++r) {
                int row = bm + wm * 64 + m * 16 + quad * 4 + r;
                int col = bn + wn * 64 + j * 16 + l15;
                float val = acc[m][j][r];
                if (HAS_BIAS && col < nbias) val += bias[col];
                if (EPI == 2) {
                    // K frag layout, head bh=b*16+h: [tile s/64][dim-chunk d/8][key s%64][d%8]
                    int bb = row >> 11, s = row & 2047, hh = col >> 7, d = col & 127;
                    size_t idx = ((size_t)((bb << 4) + hh) << 18) + ((size_t)(s >> 6) << 13)
                               + ((d >> 3) << 9) + ((s & 63) << 3) + (d & 7);
                    ((unsigned short*)Cout)[idx] = f2bf(val);
                } else if (EPI == 3) {
                    // V frag layout, head bh: [tile s/64][key-chunk (s%64)/8][dim d(128)][s%8]
                    int bb = row >> 11, s = row & 2047, hh = col >> 7, d = col & 127;
                    size_t idx = ((size_t)((bb << 4) + hh) << 18) + ((size_t)(s >> 6) << 13)
                               + (((s >> 3) & 7) << 10) + (d << 3) + (s & 7);
                    ((unsigned short*)Cout)[idx] = f2bf(val);
                } else if (EPI == 1) {
                    ((float*)Cout)[(size_t)row * ldc + col] = val;
                } else {
                    ((unsigned short*)Cout)[(size_t)row * ldc + col] = f2bf(val);
                }
            }
}

// ---------------- MFMA flash attention: fixed-offset softmax, MFMA row-sum ----------------
// grid 1024 blocks (32 bh x 32 q-tiles of 64), 256 threads (4 waves x 16 queries).
__global__ __launch_bounds__(256) void flash_attn_mfma_kernel(
    const unsigned short* __restrict__ q,
    const unsigned short* __restrict__ kswz,
    const unsigned short* __restrict__ vswz,
    unsigned short* __restrict__ o)
{
    __shared__ __align__(16) unsigned short Kl[2][8192];    // 32 KB dbuf [chunk16][key64][8]
    __shared__ __align__(16) unsigned short Vl[8192];       // 16 KB [chunk8][dim128][8]
    __shared__ __align__(16) unsigned short Ps[4][16][72];  // wave-private P

    const int tid  = threadIdx.x;
    const int wave = tid >> 6;
    const int lane = tid & 63;
    const int quad = lane >> 4, l15 = lane & 15;

    const int bid = blockIdx.x;
    const int qt = 31 - (bid >> 5);     // longest tiles dispatch first
    const int bh = bid & 31;            // head pinned to one XCD-L2
    const int b  = bh >> 4, h = bh & 15;
    const int q0 = qt * 64;

    const unsigned short* qbase = q + (size_t)(b * PS + q0) * PNCAT + h * PHD;
    const unsigned short* kbase = kswz + ((size_t)bh << 18);
    const unsigned short* vbase = vswz + ((size_t)bh << 18);

    auto stageK = [&](int it, int buf) {
        const unsigned short* kt = kbase + ((size_t)it << 13);
#pragma unroll
        for (int j = 0; j < 4; ++j)
            gl_lds16(kt + (wave * 4 + j) * 512 + lane * 8, &Kl[buf][(wave * 4 + j) * 512]);
    };
    auto stageV = [&](int it) {
        const unsigned short* vt = vbase + ((size_t)it << 13);
#pragma unroll
        for (int j = 0; j < 4; ++j)
            gl_lds16(vt + (wave * 4 + j) * 512 + lane * 8, &Vl[(wave * 4 + j) * 512]);
    };

    // Q A-frags: registers for whole kernel
    bf16x8 aq[4];
#pragma unroll
    for (int kk = 0; kk < 4; ++kk)
        aq[kk] = *(const bf16x8*)(qbase + (size_t)(wave * 16 + l15) * PNCAT + kk * 32 + quad * 8);

    bf16x8 vones;
#pragma unroll
    for (int j = 0; j < 8; ++j) vones[j] = (short)0x3F80;

    f32x4 oacc[8] = {};
    f32x4 lacc = {};

    stageK(0, 0);   // prologue prefetch

    for (int it = 0; it <= qt; ++it) {
        const int cur = it & 1;
        __syncthreads();   // B1: K[it] visible; prior-iter Vl readers done
        stageV(it);
        if (it < qt) stageK(it + 1, cur ^ 1);

        // ---- S = Q K^T on Kl[cur] ----
        f32x4 sacc[4] = {};
#pragma unroll
        for (int kk = 0; kk < 4; ++kk)
#pragma unroll
            for (int n = 0; n < 4; ++n) {
                bf16x8 bk = *(const bf16x8*)&Kl[cur][((kk * 4 + quad) * 64 + n * 16 + l15) * 8];
                sacc[n] = __builtin_amdgcn_mfma_f32_16x16x32_bf16(aq[kk], bk, sacc[n], 0, 0, 0);
            }

        // ---- P = exp(s*scale - MOFF); causal zero on diagonal tile; write to LDS ----
        const bool diag = (it == qt);
#pragma unroll
        for (int n = 0; n < 4; ++n)
#pragma unroll
            for (int r = 0; r < 4; ++r) {
                float p = __expf(fmaf(sacc[n][r], ATT_SCALE, -ATT_MOFF));
                if (diag && (n * 16 + l15 > wave * 16 + quad * 4 + r)) p = 0.0f;
                Ps[wave][quad * 4 + r][n * 16 + l15] = f2bf(p);  // wave-private
            }

        __syncthreads();   // B2: V[it] visible (loads had QK+exp in flight)

        // ---- O += P V ; l += P 1 (row-sum via ones MFMA) ----
#pragma unroll
        for (int kk = 0; kk < 2; ++kk) {
            bf16x8 ap = *(const bf16x8*)&Ps[wave][l15][kk * 32 + quad * 8];
            lacc = __builtin_amdgcn_mfma_f32_16x16x32_bf16(ap, vones, lacc, 0, 0, 0);
#pragma unroll
            for (int n = 0; n < 8; ++n) {
                bf16x8 bv = *(const bf16x8*)&Vl[((kk * 4 + quad) * 128 + n * 16 + l15) * 8];
                oacc[n] = __builtin_amdgcn_mfma_f32_16x16x32_bf16(ap, bv, oacc[n], 0, 0, 0);
            }
        }
    }

    // ---- epilogue: normalize by l, store bf16 ----
    float inv[4];
#pragma unroll
    for (int r = 0; r < 4; ++r) inv[r] = 1.0f / lacc[r];
#pragma unroll
    for (int n = 0; n < 8; ++n)
#pragma unroll
        for (int r = 0; r < 4; ++r) {
            int row = q0 + wave * 16 + quad * 4 + r;
            int col = h * PHD + n * 16 + l15;
            o[(size_t)(b * PS + row) * PH + col] = f2bf(oacc[n][r] * inv[r]);
        }
}

// ---------------- host launcher ----------------
extern "C" void kernel_launch(void* const* d_in, const int* in_sizes, int n_in,
                              void* d_out, int out_size, void* d_ws, size_t ws_size,
                              hipStream_t stream)
{
    const float* x      = (const float*)d_in[0];
    const float* wq     = (const float*)d_in[1];
    const float* bq     = (const float*)d_in[2];
    const float* wk_lat = (const float*)d_in[3];
    const float* wv_lat = (const float*)d_in[4];
    const float* wk     = (const float*)d_in[5];
    const float* wv     = (const float*)d_in[6];
    const float* wo     = (const float*)d_in[7];
    const float* bo     = (const float*)d_in[8];
    float* out = (float*)d_out;

    char* ws = (char*)d_ws;
    size_t off = 0;
    auto alloc = [&](size_t bytes) -> void* {
        void* p = ws + off;
        off += (bytes + 255) & ~(size_t)255;
        return p;
    };
    unsigned short* xb    = (unsigned short*)alloc((size_t)PM * PH * 2);       // 16 MB
    unsigned short* wcatT = (unsigned short*)alloc((size_t)PNCAT * PH * 2);    // 12 MB
    unsigned short* wkT   = (unsigned short*)alloc((size_t)PH * PLD * 2);      // 2 MB
    unsigned short* wvT   = (unsigned short*)alloc((size_t)PH * PLD * 2);      // 2 MB
    unsigned short* woT   = (unsigned short*)alloc((size_t)PH * PH * 2);       // 8 MB
    unsigned short* cat   = (unsigned short*)alloc((size_t)PM * PNCAT * 2);    // 24 MB
    unsigned short* kswz  = (unsigned short*)alloc((size_t)PM * PH * 2);       // 16 MB
    unsigned short* attn  = (unsigned short*)alloc((size_t)PM * PH * 2);       // 16 MB
    // vswz aliases xb: xb dead after the merged down-proj reads it.
    unsigned short* vswz  = xb;

    unsigned short* wqT    = wcatT;                                  // rows 0..2047
    unsigned short* wkLatT = wcatT + (size_t)PH * PH;                // rows 2048..2559
    unsigned short* wvLatT = wcatT + (size_t)(PH + PLD) * PH;        // rows 2560..3071

    dim3 tb(32, 8);

    // 1. cast x -> bf16
    cast_f32_bf16_kernel<<<(PM * PH) / 4 / 256, 256, 0, stream>>>(x, xb, PM * PH);
    // 2. transpose weights -> bf16 B^T layouts
    transpose_cast_kernel<<<dim3(PH / 32,  PH / 32),  tb, 0, stream>>>(wq,     wqT,    PH,  PH);
    transpose_cast_kernel<<<dim3(PLD / 32, PH / 32),  tb, 0, stream>>>(wk_lat, wkLatT, PH,  PLD);
    transpose_cast_kernel<<<dim3(PLD / 32, PH / 32),  tb, 0, stream>>>(wv_lat, wvLatT, PH,  PLD);
    transpose_cast_kernel<<<dim3(PH / 32,  PLD / 32), tb, 0, stream>>>(wk,     wkT,    PLD, PH);
    transpose_cast_kernel<<<dim3(PH / 32,  PLD / 32), tb, 0, stream>>>(wv,     wvT,    PLD, PH);
    transpose_cast_kernel<<<dim3(PH / 32,  PH / 32),  tb, 0, stream>>>(wo,     woT,    PH,  PH);

    // 3. merged down-projection: cat[M][3072] = xb @ [wq | wk_lat | wv_lat] (+bq on first 2048)
    //    128x128 tile -> grid 24x32 = 768 WGs = exactly 3/CU co-resident
    gemm97_kernel<0, true><<<dim3(PNCAT / 128, PM / 128), 256, 0, stream>>>(
        xb, PH, wcatT, bq, PH, cat, PNCAT, PH);

    // 4. up-projections straight into MFMA-fragment-swizzled K / V (512 WGs, 2/CU)
    gemm97_kernel<2, false><<<dim3(PH / 128, PM / 128), 256, 0, stream>>>(
        cat + PH, PNCAT, wkT, nullptr, 0, kswz, 0, PLD);
    gemm97_kernel<3, false><<<dim3(PH / 128, PM / 128), 256, 0, stream>>>(
        cat + PH + PLD, PNCAT, wvT, nullptr, 0, vswz, 0, PLD);

    // 5. causal MFMA flash attention
    flash_attn_mfma_kernel<<<PB * PNH * (PS / 64), 256, 0, stream>>>(cat, kswz, vswz, attn);

    // 6. output projection (fp32 out + bo), 512 WGs
    gemm97_kernel<1, true><<<dim3(PH / 128, PM / 128), 256, 0, stream>>>(
        attn, PH, woT, bo, PH, out, PH, PH);
}

// Round 7
// 337.101 us; speedup vs baseline: 1.0190x; 1.0190x over previous
//
#include <hip/hip_runtime.h>
#include <hip/hip_bf16.h>

// ---------------- constants (problem shape) ----------------
// B=2, S=2048, H=2048, NH=16, LD=512, HD=128
#define PB   2
#define PS   2048
#define PH   2048
#define PNH  16
#define PLD  512
#define PHD  128
#define PM   (PB * PS)          // 4096 rows in all GEMMs
#define PNCAT 3072              // merged down-proj width: 2048 q + 512 klat + 512 vlat
#define ATT_SCALE 0.08838834764831845f  // 1/sqrt(128)
#define ATT_MOFF 4.0f
// exp(s*SCALE - MOFF) == exp2(s*SC2 - MO2): fold log2(e) into the constants
#define ATT_SC2  0.12751744f    // ATT_SCALE * log2(e)
#define ATT_MO2  5.77078016f    // ATT_MOFF  * log2(e)

typedef __attribute__((ext_vector_type(8))) short bf16x8;
typedef __attribute__((ext_vector_type(4))) float f32x4;

__device__ __forceinline__ unsigned short f2bf(float f) {
    unsigned int u = __float_as_uint(f);
    u += 0x7FFFu + ((u >> 16) & 1u);   // RNE
    return (unsigned short)(u >> 16);
}

// async global->LDS, 16 B per lane; LDS dest = wave-uniform base + lane*16
__device__ __forceinline__ void gl_lds16(const unsigned short* g, unsigned short* l) {
    __builtin_amdgcn_global_load_lds(
        (const __attribute__((address_space(1))) unsigned int*)g,
        (__attribute__((address_space(3))) unsigned int*)l, 16, 0, 0);
}

#define VMCNT(n)     asm volatile("s_waitcnt vmcnt(" #n ")" ::: "memory")
#define MEMFENCE()   asm volatile("" ::: "memory")

// ---------------- cast fp32 -> bf16 (elementwise, 4/thread) ----------------
__global__ __launch_bounds__(256) void cast_f32_bf16_kernel(
    const float* __restrict__ in, unsigned short* __restrict__ out, int n)
{
    int i = (blockIdx.x * 256 + threadIdx.x) * 4;
    if (i >= n) return;
    float4 f = *(const float4*)(in + i);
    unsigned int a = (unsigned int)f2bf(f.x) | ((unsigned int)f2bf(f.y) << 16);
    unsigned int b = (unsigned int)f2bf(f.z) | ((unsigned int)f2bf(f.w) << 16);
    *(uint2*)(out + i) = make_uint2(a, b);
}

// ---------------- merged transpose+cast: 6 independent fp32 [R][C] -> bf16 [C][R] ----------------
struct TC6 {
    const float* src[6];
    unsigned short* dst[6];
    int R[6];
    int C[6];
};

__global__ __launch_bounds__(256) void transpose_cast6_kernel(TC6 p)
{
    __shared__ float tile[32][33];
    const int z = blockIdx.z;
    const int r0 = blockIdx.y * 32, c0 = blockIdx.x * 32;
    const int R = p.R[z], C = p.C[z];
    if (r0 >= R || c0 >= C) return;     // uniform early-exit for oversized grid
    const float* in = p.src[z];
    unsigned short* out = p.dst[z];
    int tx = threadIdx.x, ty = threadIdx.y;
#pragma unroll
    for (int i = 0; i < 32; i += 8)
        tile[ty + i][tx] = in[(size_t)(r0 + ty + i) * C + (c0 + tx)];
    __syncthreads();
#pragma unroll
    for (int i = 0; i < 32; i += 8)
        out[(size_t)(c0 + ty + i) * R + (r0 + tx)] = f2bf(tile[tx][ty + i]);
}

// ---------------- m97-structure bf16 MFMA GEMM: 128x128, multi-WG TLP ----------------
// (unchanged from R6 -- knocked all GEMMs below the attention dispatch)
// EPI: 0 = bf16 row-major, 1 = fp32 row-major, 2 = K-swizzled, 3 = V-swizzled.
template<int EPI, bool HAS_BIAS>
__global__ __launch_bounds__(256, 3) void gemm97_kernel(
    const unsigned short* __restrict__ A, int lda,
    const unsigned short* __restrict__ BT,
    const float* __restrict__ bias, int nbias,
    void* __restrict__ Cout, int ldc, int K)
{
    __shared__ __align__(16) unsigned short As[128 * 64];   // 16 KiB
    __shared__ __align__(16) unsigned short Bs[128 * 64];   // 16 KiB

    const int tid  = threadIdx.x;
    const int wave = tid >> 6, lane = tid & 63;
    const int wm = wave >> 1, wn = wave & 1;
    const int quad = lane >> 4, l15 = lane & 15;
    const int sw = l15 & 7;        // read-side XOR (== row&7 of every frag row)

    // bijective XCD-aware swizzle of the linear workgroup id
    const int gx  = gridDim.x;
    const int nwg = gx * gridDim.y;
    int wg = blockIdx.y * gx + blockIdx.x;
    if (!(nwg & 7)) wg = (wg & 7) * (nwg >> 3) + (wg >> 3);
    const int bm = (wg / gx) * 128, bn = (wg % gx) * 128;

    const int nt = K >> 6;

    // staging: thread t covers (row = t>>3 in 0..31, 16B-slot p = t&7) of a
    // 32x64 sweep; 4 sweeps cover 128 rows.  LDS dest linear => fetch the
    // pre-swizzled global column (phys slot p holds logical slot p^(row&7)).
    const int srow = tid >> 3;
    const int scol = ((tid & 7) ^ (srow & 7)) << 3;  // elements; (srow+32k)&7 invariant
    const unsigned short* Ag = A  + (size_t)(bm + srow) * lda + scol;
    const unsigned short* Bg = BT + (size_t)(bn + srow) * K   + scol;
    unsigned short* const ldsA = &As[wave * 512];
    unsigned short* const ldsB = &Bs[wave * 512];

    // fragment reads: logical (row, slot s=ks*4+quad) -> physical slot s^(row&7)
    auto ldA = [&](int m, int ks) -> bf16x8 {
        int ra = wm * 64 + m * 16 + l15;
        return *(const bf16x8*)&As[ra * 64 + (((ks * 4 + quad) ^ sw) << 3)];
    };
    auto ldB = [&](int j, int ks) -> bf16x8 {
        int rb = wn * 64 + j * 16 + l15;
        return *(const bf16x8*)&Bs[rb * 64 + (((ks * 4 + quad) ^ sw) << 3)];
    };

    f32x4 acc[4][4] = {};

    for (int kt = 0; kt < nt; ++kt) {
        const int k0 = kt * 64;
        // ---- stage tile kt: 4 sweeps x (A,B), 8 x global_load_lds ----
#pragma unroll
        for (int s = 0; s < 4; ++s) {
            gl_lds16(Ag + (size_t)(s * 32) * lda + k0, ldsA + s * 2048);
            gl_lds16(Bg + (size_t)(s * 32) * K   + k0, ldsB + s * 2048);
        }
        VMCNT(0);
        __syncthreads();   // tile visible to all waves

        // ---- compute: 16 ds_read_b128 + 32 MFMA, compiler-scheduled ----
        bf16x8 bfr[4][2];
#pragma unroll
        for (int j = 0; j < 4; ++j)
#pragma unroll
            for (int ks = 0; ks < 2; ++ks) bfr[j][ks] = ldB(j, ks);
#pragma unroll
        for (int m = 0; m < 4; ++m) {
            bf16x8 a0 = ldA(m, 0), a1 = ldA(m, 1);
#pragma unroll
            for (int j = 0; j < 4; ++j) {
                acc[m][j] = __builtin_amdgcn_mfma_f32_16x16x32_bf16(a0, bfr[j][0], acc[m][j], 0, 0, 0);
                acc[m][j] = __builtin_amdgcn_mfma_f32_16x16x32_bf16(a1, bfr[j][1], acc[m][j], 0, 0, 0);
            }
        }
        __syncthreads();   // all reads done before next tile's staging lands
    }

    // ---------- epilogue ----------
#pragma unroll
    for (int m = 0; m < 4; ++m)
#pragma unroll
        for (int j = 0; j < 4; ++j)
#pragma unroll
            for (int r = 0; r < 4; ++r) {
                int row = bm + wm * 64 + m * 16 + quad * 4 + r;
                int col = bn + wn * 64 + j * 16 + l15;
                float val = acc[m][j][r];
                if (HAS_BIAS && col < nbias) val += bias[col];
                if (EPI == 2) {
                    // K frag layout, head bh=b*16+h: [tile s/64][dim-chunk d/8][key s%64][d%8]
                    int bb = row >> 11, s = row & 2047, hh = col >> 7, d = col & 127;
                    size_t idx = ((size_t)((bb << 4) + hh) << 18) + ((size_t)(s >> 6) << 13)
                               + ((d >> 3) << 9) + ((s & 63) << 3) + (d & 7);
                    ((unsigned short*)Cout)[idx] = f2bf(val);
                } else if (EPI == 3) {
                    // V frag layout, head bh: [tile s/64][key-chunk (s%64)/8][dim d(128)][s%8]
                    int bb = row >> 11, s = row & 2047, hh = col >> 7, d = col & 127;
                    size_t idx = ((size_t)((bb << 4) + hh) << 18) + ((size_t)(s >> 6) << 13)
                               + (((s >> 3) & 7) << 10) + (d << 3) + (s & 7);
                    ((unsigned short*)Cout)[idx] = f2bf(val);
                } else if (EPI == 1) {
                    ((float*)Cout)[(size_t)row * ldc + col] = val;
                } else {
                    ((unsigned short*)Cout)[(size_t)row * ldc + col] = f2bf(val);
                }
            }
}

// ---------------- MFMA flash attention: single-buffer K, 3 WGs/CU ----------------
// grid 1024 blocks (32 bh x 32 q-tiles of 64), 256 threads (4 waves x 16 queries).
// R6 lesson (same as GEMM): 2 WGs/CU starved the drain windows.  LDS cut to
// 42 KiB -> 3 WGs/CU; per iter: stage K then V -> vmcnt(4) (K resident, V in
// flight) + raw s_barrier (NOT __syncthreads: that drains vmcnt to 0) ->
// QK^T+exp cover V latency -> __syncthreads (drains V) -> PV.  Ps stride 76
// (38 dwords, 6*l15 mod 32 all-distinct) kills the P-read bank conflicts.
__global__ __launch_bounds__(256, 3) void flash_attn_mfma_kernel(
    const unsigned short* __restrict__ q,
    const unsigned short* __restrict__ kswz,
    const unsigned short* __restrict__ vswz,
    unsigned short* __restrict__ o)
{
    __shared__ __align__(16) unsigned short Kl[8192];       // 16 KB [chunk16][key64][8]
    __shared__ __align__(16) unsigned short Vl[8192];       // 16 KB [chunk8][dim128][8]
    __shared__ __align__(16) unsigned short Ps[4][16][76];  // wave-private P, conflict-free stride

    const int tid  = threadIdx.x;
    const int wave = tid >> 6;
    const int lane = tid & 63;
    const int quad = lane >> 4, l15 = lane & 15;

    const int bid = blockIdx.x;
    const int qt = 31 - (bid >> 5);     // longest tiles dispatch first
    const int bh = bid & 31;            // head pinned to one XCD-L2
    const int b  = bh >> 4, h = bh & 15;
    const int q0 = qt * 64;

    const unsigned short* qbase = q + (size_t)(b * PS + q0) * PNCAT + h * PHD;
    const unsigned short* kbase = kswz + ((size_t)bh << 18);
    const unsigned short* vbase = vswz + ((size_t)bh << 18);

    auto stageK = [&](int it) {
        const unsigned short* kt = kbase + ((size_t)it << 13);
#pragma unroll
        for (int j = 0; j < 4; ++j)
            gl_lds16(kt + (wave * 4 + j) * 512 + lane * 8, &Kl[(wave * 4 + j) * 512]);
    };
    auto stageV = [&](int it) {
        const unsigned short* vt = vbase + ((size_t)it << 13);
#pragma unroll
        for (int j = 0; j < 4; ++j)
            gl_lds16(vt + (wave * 4 + j) * 512 + lane * 8, &Vl[(wave * 4 + j) * 512]);
    };

    // Q A-frags: registers for whole kernel
    bf16x8 aq[4];
#pragma unroll
    for (int kk = 0; kk < 4; ++kk)
        aq[kk] = *(const bf16x8*)(qbase + (size_t)(wave * 16 + l15) * PNCAT + kk * 32 + quad * 8);

    bf16x8 vones;
#pragma unroll
    for (int j = 0; j < 8; ++j) vones[j] = (short)0x3F80;

    f32x4 oacc[8] = {};
    f32x4 lacc = {};

    for (int it = 0; it <= qt; ++it) {
        __syncthreads();   // S0: prior iter's K/V readers retired (full drain is free here)
        stageK(it);        // issued first -> oldest 4 vm ops
        stageV(it);        // next 4, stay in flight through QK^T
        VMCNT(4);          // K resident; V outstanding
        __builtin_amdgcn_s_barrier();   // S1: K visible to all waves
        MEMFENCE();

        // ---- S = Q K^T on Kl ----
        f32x4 sacc[4] = {};
#pragma unroll
        for (int kk = 0; kk < 4; ++kk)
#pragma unroll
            for (int n = 0; n < 4; ++n) {
                bf16x8 bk = *(const bf16x8*)&Kl[((kk * 4 + quad) * 64 + n * 16 + l15) * 8];
                sacc[n] = __builtin_amdgcn_mfma_f32_16x16x32_bf16(aq[kk], bk, sacc[n], 0, 0, 0);
            }

        // ---- P = exp2(s*sc2 - mo2); causal zero on diagonal tile; write to LDS ----
        const bool diag = (it == qt);
#pragma unroll
        for (int n = 0; n < 4; ++n)
#pragma unroll
            for (int r = 0; r < 4; ++r) {
                float p = exp2f(fmaf(sacc[n][r], ATT_SC2, -ATT_MO2));
                if (diag && (n * 16 + l15 > wave * 16 + quad * 4 + r)) p = 0.0f;
                Ps[wave][quad * 4 + r][n * 16 + l15] = f2bf(p);  // wave-private
            }

        __syncthreads();   // S2: drains V loads (vmcnt 0) + makes Vl visible

        // ---- O += P V ; l += P 1 (row-sum via ones MFMA) ----
#pragma unroll
        for (int kk = 0; kk < 2; ++kk) {
            bf16x8 ap = *(const bf16x8*)&Ps[wave][l15][kk * 32 + quad * 8];
            lacc = __builtin_amdgcn_mfma_f32_16x16x32_bf16(ap, vones, lacc, 0, 0, 0);
#pragma unroll
            for (int n = 0; n < 8; ++n) {
                bf16x8 bv = *(const bf16x8*)&Vl[((kk * 4 + quad) * 128 + n * 16 + l15) * 8];
                oacc[n] = __builtin_amdgcn_mfma_f32_16x16x32_bf16(ap, bv, oacc[n], 0, 0, 0);
            }
        }
    }

    // ---- epilogue: normalize by l, store bf16 ----
    float inv[4];
#pragma unroll
    for (int r = 0; r < 4; ++r) inv[r] = 1.0f / lacc[r];
#pragma unroll
    for (int n = 0; n < 8; ++n)
#pragma unroll
        for (int r = 0; r < 4; ++r) {
            int row = q0 + wave * 16 + quad * 4 + r;
            int col = h * PHD + n * 16 + l15;
            o[(size_t)(b * PS + row) * PH + col] = f2bf(oacc[n][r] * inv[r]);
        }
}

// ---------------- host launcher ----------------
extern "C" void kernel_launch(void* const* d_in, const int* in_sizes, int n_in,
                              void* d_out, int out_size, void* d_ws, size_t ws_size,
                              hipStream_t stream)
{
    const float* x      = (const float*)d_in[0];
    const float* wq     = (const float*)d_in[1];
    const float* bq     = (const float*)d_in[2];
    const float* wk_lat = (const float*)d_in[3];
    const float* wv_lat = (const float*)d_in[4];
    const float* wk     = (const float*)d_in[5];
    const float* wv     = (const float*)d_in[6];
    const float* wo     = (const float*)d_in[7];
    const float* bo     = (const float*)d_in[8];
    float* out = (float*)d_out;

    char* ws = (char*)d_ws;
    size_t off = 0;
    auto alloc = [&](size_t bytes) -> void* {
        void* p = ws + off;
        off += (bytes + 255) & ~(size_t)255;
        return p;
    };
    unsigned short* xb    = (unsigned short*)alloc((size_t)PM * PH * 2);       // 16 MB
    unsigned short* wcatT = (unsigned short*)alloc((size_t)PNCAT * PH * 2);    // 12 MB
    unsigned short* wkT   = (unsigned short*)alloc((size_t)PH * PLD * 2);      // 2 MB
    unsigned short* wvT   = (unsigned short*)alloc((size_t)PH * PLD * 2);      // 2 MB
    unsigned short* woT   = (unsigned short*)alloc((size_t)PH * PH * 2);       // 8 MB
    unsigned short* cat   = (unsigned short*)alloc((size_t)PM * PNCAT * 2);    // 24 MB
    unsigned short* kswz  = (unsigned short*)alloc((size_t)PM * PH * 2);       // 16 MB
    unsigned short* attn  = (unsigned short*)alloc((size_t)PM * PH * 2);       // 16 MB
    // vswz aliases xb: xb dead after the merged down-proj reads it.
    unsigned short* vswz  = xb;

    unsigned short* wqT    = wcatT;                                  // rows 0..2047
    unsigned short* wkLatT = wcatT + (size_t)PH * PH;                // rows 2048..2559
    unsigned short* wvLatT = wcatT + (size_t)(PH + PLD) * PH;        // rows 2560..3071

    // 1. cast x -> bf16
    cast_f32_bf16_kernel<<<(PM * PH) / 4 / 256, 256, 0, stream>>>(x, xb, PM * PH);

    // 2. all six weight transposes in ONE launch (grid-z dispatch, early-exit)
    TC6 tc;
    tc.src[0] = wq;     tc.dst[0] = wqT;    tc.R[0] = PH;  tc.C[0] = PH;
    tc.src[1] = wk_lat; tc.dst[1] = wkLatT; tc.R[1] = PH;  tc.C[1] = PLD;
    tc.src[2] = wv_lat; tc.dst[2] = wvLatT; tc.R[2] = PH;  tc.C[2] = PLD;
    tc.src[3] = wk;     tc.dst[3] = wkT;    tc.R[3] = PLD; tc.C[3] = PH;
    tc.src[4] = wv;     tc.dst[4] = wvT;    tc.R[4] = PLD; tc.C[4] = PH;
    tc.src[5] = wo;     tc.dst[5] = woT;    tc.R[5] = PH;  tc.C[5] = PH;
    transpose_cast6_kernel<<<dim3(64, 64, 6), dim3(32, 8), 0, stream>>>(tc);

    // 3. merged down-projection: cat[M][3072] = xb @ [wq | wk_lat | wv_lat] (+bq on first 2048)
    //    128x128 tile -> grid 24x32 = 768 WGs = exactly 3/CU co-resident
    gemm97_kernel<0, true><<<dim3(PNCAT / 128, PM / 128), 256, 0, stream>>>(
        xb, PH, wcatT, bq, PH, cat, PNCAT, PH);

    // 4. up-projections straight into MFMA-fragment-swizzled K / V (512 WGs, 2/CU)
    gemm97_kernel<2, false><<<dim3(PH / 128, PM / 128), 256, 0, stream>>>(
        cat + PH, PNCAT, wkT, nullptr, 0, kswz, 0, PLD);
    gemm97_kernel<3, false><<<dim3(PH / 128, PM / 128), 256, 0, stream>>>(
        cat + PH + PLD, PNCAT, wvT, nullptr, 0, vswz, 0, PLD);

    // 5. causal MFMA flash attention (3 WGs/CU, single-buffer K)
    flash_attn_mfma_kernel<<<PB * PNH * (PS / 64), 256, 0, stream>>>(cat, kswz, vswz, attn);

    // 6. output projection (fp32 out + bo), 512 WGs
    gemm97_kernel<1, true><<<dim3(PH / 128, PM / 128), 256, 0, stream>>>(
        attn, PH, woT, bo, PH, out, PH, PH);
}